// Round 8
// baseline (830.936 us; speedup 1.0000x reference)
//
#include <hip/hip_runtime.h>
#include <hip/hip_fp16.h>

#define M_TOTAL 4096
#define N_TOTAL 11008
#define K_TOTAL 4096
#define KPACK   2048     // int32 cols; each int32 holds ONE byte = 2 nibbles

typedef _Float16 f16x4 __attribute__((ext_vector_type(4)));
typedef _Float16 f16x8 __attribute__((ext_vector_type(8)));
typedef float    f32x4 __attribute__((ext_vector_type(4)));

// ---------------- async 16B global -> LDS ----------------
__device__ __forceinline__ void load16_to_lds(const void* g, void* l) {
    __builtin_amdgcn_global_load_lds(
        (const __attribute__((address_space(1))) unsigned int*)g,
        (__attribute__((address_space(3))) unsigned int*)l,
        16, 0, 0);
}

// ---------------- prepass 1: x fp32 -> f16 (16.7M elems, 8/thread) ----------------
__global__ __launch_bounds__(256)
void _Int4Linear_cvt_x(const float* __restrict__ x, _Float16* __restrict__ xf) {
    const size_t i = ((size_t)blockIdx.x * 256 + threadIdx.x) * 8;
    const float4 v0 = *(const float4*)(x + i);
    const float4 v1 = *(const float4*)(x + i + 4);
    f16x8 h = { (_Float16)v0.x, (_Float16)v0.y, (_Float16)v0.z, (_Float16)v0.w,
                (_Float16)v1.x, (_Float16)v1.y, (_Float16)v1.z, (_Float16)v1.w };
    *(f16x8*)(xf + i) = h;
}

// ---------------- prepass 2: wp int32 -> f16 pairs (22.5M int32, 4/thread) ----------------
__global__ __launch_bounds__(256)
void _Int4Linear_dequant_w(const int* __restrict__ wp, _Float16* __restrict__ wf) {
    const size_t i = ((size_t)blockIdx.x * 256 + threadIdx.x) * 4;   // int32 index
    const int4 p = *(const int4*)(wp + i);
    const int v[4] = { p.x, p.y, p.z, p.w };
    f16x8 h;
    #pragma unroll
    for (int j = 0; j < 4; ++j) {
        h[2 * j]     = (_Float16)(( v[j]       & 15) - 8);
        h[2 * j + 1] = (_Float16)(((v[j] >> 4) & 15) - 8);
    }
    *(f16x8*)(wf + i * 2) = h;   // each int32 -> 2 f16
}

// ---------------- main GEMM: 256x256 tile; A via LDS, B DIRECT global->regs ----------------
// R8 = R7 design, compile-fixed (R7's #pragma-inside-#define never compiled).
// Rationale: R2-R5 plateaued at ~45% MfmaUtil = serial {ds_read 96KB ~1150cyc} +
// {MFMA ~1100} + {stage-writes ~300} per phase; LDS pipe (~85 B/cyc) is co-bottleneck.
// B-fragments are cache-line-perfect from row-major B (4 lanes x 16B = 64B/row) and
// L2/L3-resident -> load straight to registers (compiler-tracked vector loads),
// prefetched ONE PHASE AHEAD into the idle half of a double-buffer (bA/bB).
// B's LDS round-trip (16KB write + 32KB read per CU-phase) disappears (-37% LDS traffic),
// and the MFMA chain's lgkm dependence is A-only -> first MFMA waits on 1 ds_read.
// vmcnt discipline (order-robust): each phase issues exactly 6 VMEM (4 B-loads +
// 2 gload_lds), all fenced inside the phase by memory-clobbered asm + sched_barrier(0).
// ONE `vmcnt(6)` per phase == "all older phases drained" == A-slot staged last phase
// landed (own wave); end-of-phase s_barrier makes that cross-wave. Compiler inserts its
// own counted waits for the B-register reads (they're tracked loads).
// LDS: 4 x 16KB A-slots (64 KB): slot s read at phase p%4==s, staged at p-2, restaged
// at p+2 (>=2 barriers between read and restage: WAR safe).
#define BM 256
#define BN 256
#define NKT 64          // K / 64

__device__ __forceinline__ void gphase(const char* slotR, char* slotW,
                                       f16x8 (&bcur)[4], f16x8 (&bnxt)[4],
                                       const _Float16* Bf0, const _Float16* Bf1,
                                       const _Float16* Bf2, const _Float16* Bf3,
                                       int koffB,
                                       const _Float16* Ab, int koffS, int ldst, int aoff,
                                       f32x4 (&acc)[8][4])
{
    // prefetch next phase's B-frags (read 1 phase later; compiler tracks the wait)
    bnxt[0] = *(const f16x8*)(Bf0 + koffB);
    bnxt[1] = *(const f16x8*)(Bf1 + koffB);
    bnxt[2] = *(const f16x8*)(Bf2 + koffB);
    bnxt[3] = *(const f16x8*)(Bf3 + koffB);
    // stage A for phase p+2 (linear LDS dest, pre-swizzled global source)
    load16_to_lds(Ab + koffS,                             slotW + ldst);
    load16_to_lds(Ab + (size_t)128 * K_TOTAL + koffS,     slotW + 8192 + ldst);
    // A fragments for THIS phase (slot staged at p-2, drained at p-1, barrier'd)
    f16x8 a[8];
    #pragma unroll
    for (int f = 0; f < 8; ++f) a[f] = *(const f16x8*)(slotR + aoff + f * 1024);
    asm volatile("s_waitcnt vmcnt(6)" ::: "memory");   // drain all VMEM older than this phase
    __builtin_amdgcn_sched_barrier(0);                 // rule #18: nothing hoists past the wait
    __builtin_amdgcn_s_setprio(1);
    #pragma unroll
    for (int mf = 0; mf < 8; ++mf)
        #pragma unroll
        for (int nf = 0; nf < 4; ++nf)
            acc[mf][nf] = __builtin_amdgcn_mfma_f32_16x16x32_f16(a[mf], bcur[nf], acc[mf][nf], 0, 0, 0);
    __builtin_amdgcn_s_setprio(0);
    __builtin_amdgcn_s_barrier();                      // frees slotR for restage at p+2
    __builtin_amdgcn_sched_barrier(0);
}

__global__ __launch_bounds__(512, 2)
void _Int4Linear_54631984005366_kernel(const _Float16* __restrict__ A,   // [M][K] f16
                                       const _Float16* __restrict__ B,   // [N][K] f16
                                       const float* __restrict__ scale,
                                       const float* __restrict__ bias,
                                       float*       __restrict__ out)
{
    extern __shared__ char sm[];     // A slots: sm + s*16384, s = 0..3
    char* const slot0 = sm;
    char* const slot1 = sm + 16384;
    char* const slot2 = sm + 32768;
    char* const slot3 = sm + 49152;

    const int t    = threadIdx.x;
    const int wave = t >> 6;
    const int lane = t & 63;
    const int l16  = lane & 15;
    const int quad = lane >> 4;
    const int wm   = wave >> 2;        // 0..1
    const int wn   = wave & 3;         // 0..3

    // XCD-aware bijective swizzle: 688 = 8 * 86 exactly; nT-major (16 consecutive share B-panel)
    const int b0 = blockIdx.x;
    const int sw = (b0 & 7) * 86 + (b0 >> 3);
    const int mBase = (sw & 15) * BM;   // 16 m-tiles
    const int nBase = (sw >> 4) * BN;   // 43 n-tiles

    // A staging: round r covers rows r*128; wave covers 16 rows (1KB), lane -> (row, chunk)
    // source chunk pre-swizzled: (lane&3) ^ ((lane>>3)&3)  == chunk ^ ((row>>1)&3)
    const int srow = wave * 16 + (lane >> 2);
    const int scol = (((lane & 3) ^ ((lane >> 3) & 3)) << 3);   // halves
    const _Float16* const Ab = A + (size_t)(mBase + srow) * K_TOTAL + scol;
    const int ldst = wave * 1024;      // + r*8192 within slot (linear dest)

    // A ds_read byte offset within a slot (swizzled chunk); slot row = 64 B
    const int chA  = (quad ^ ((l16 >> 1) & 3)) << 4;
    const int aoff = (wm * 128 + l16) * 64 + chA;

    // B fragment base pointers (per nf): row (nBase + wn*64 + nf*16 + l16), k-chunk quad*8
    // (4 lanes per row read 64B contiguous -> cache-line-perfect)
    const _Float16* const Bf0 = B + (size_t)(nBase + wn * 64 +  0 + l16) * K_TOTAL + quad * 8;
    const _Float16* const Bf1 = B + (size_t)(nBase + wn * 64 + 16 + l16) * K_TOTAL + quad * 8;
    const _Float16* const Bf2 = B + (size_t)(nBase + wn * 64 + 32 + l16) * K_TOTAL + quad * 8;
    const _Float16* const Bf3 = B + (size_t)(nBase + wn * 64 + 48 + l16) * K_TOTAL + quad * 8;

    f32x4 acc[8][4] = {};
    f16x8 bA[4], bB[4];

    // ---- prologue: B-frags for phase 0 (t=0,k0); stage slot0 (t0,k0), slot1 (t0,k1) ----
    bA[0] = *(const f16x8*)(Bf0);
    bA[1] = *(const f16x8*)(Bf1);
    bA[2] = *(const f16x8*)(Bf2);
    bA[3] = *(const f16x8*)(Bf3);
    #pragma unroll
    for (int r = 0; r < 2; ++r) load16_to_lds(Ab + (size_t)r * 128 * K_TOTAL,      slot0 + r * 8192 + ldst);
    #pragma unroll
    for (int r = 0; r < 2; ++r) load16_to_lds(Ab + (size_t)r * 128 * K_TOTAL + 32, slot1 + r * 8192 + ldst);
    asm volatile("s_waitcnt vmcnt(0)" ::: "memory");   // once per kernel: everything landed
    __builtin_amdgcn_s_barrier();
    __builtin_amdgcn_sched_barrier(0);

    for (int t0 = 0; t0 < NKT; t0 += 2) {
        const int ts2 = (t0 + 2 < NKT) ? t0 + 2 : NKT - 1;   // clamp: tail re-stages (never read)
        // phase 0: (t0,k0)   read slot0, stage slot2 <- (t0+1,k0), Bnext <- (t0,k1)
        gphase(slot0, slot2, bA, bB, Bf0, Bf1, Bf2, Bf3, t0 * 64 + 32,
               Ab, (t0 + 1) * 64,      ldst, aoff, acc);
        // phase 1: (t0,k1)   read slot1, stage slot3 <- (t0+1,k1), Bnext <- (t0+1,k0)
        gphase(slot1, slot3, bB, bA, Bf0, Bf1, Bf2, Bf3, (t0 + 1) * 64,
               Ab, (t0 + 1) * 64 + 32, ldst, aoff, acc);
        // phase 2: (t0+1,k0) read slot2, stage slot0 <- (ts2,k0),  Bnext <- (t0+1,k1)
        gphase(slot2, slot0, bA, bB, Bf0, Bf1, Bf2, Bf3, (t0 + 1) * 64 + 32,
               Ab, ts2 * 64,           ldst, aoff, acc);
        // phase 3: (t0+1,k1) read slot3, stage slot1 <- (ts2,k1),  Bnext <- (ts2,k0)
        gphase(slot3, slot1, bB, bA, Bf0, Bf1, Bf2, Bf3, ts2 * 64,
               Ab, ts2 * 64 + 32,      ldst, aoff, acc);
    }
    asm volatile("s_waitcnt vmcnt(0)" ::: "memory");   // drain clamped tail stages before exit

    // ---- epilogue: scale/bias fused, C[m][n] with col=l16, row=quad*4+r ----
    #pragma unroll
    for (int nf = 0; nf < 4; ++nf) {
        const int n = nBase + wn * 64 + nf * 16 + l16;
        const float s  = scale[n];
        const float bz = bias[n];
        #pragma unroll
        for (int mf = 0; mf < 8; ++mf) {
            const int mb = mBase + wm * 128 + mf * 16 + quad * 4;
            #pragma unroll
            for (int r = 0; r < 4; ++r)
                out[(size_t)(mb + r) * N_TOTAL + n] = acc[mf][nf][r] * s + bz;
        }
    }
}

// ---------------- fallback: self-contained (raw inputs, static 20KB LDS, no attrs) ----------------
#define FBM 128
#define FBN 128
#define FBK 32
#define LDR 40
__global__ __launch_bounds__(256)
void _Int4Linear_fallback(const float* __restrict__ x, const int* __restrict__ wp,
                          const float* __restrict__ scale, const float* __restrict__ bias,
                          float* __restrict__ out)
{
    __shared__ _Float16 As[FBM * LDR];
    __shared__ _Float16 Bs[FBN * LDR];
    const int t = threadIdx.x, wave = t >> 6, lane = t & 63;
    const int l16 = lane & 15, quad = lane >> 4;
    const int nBase = blockIdx.x * FBN, mBase = blockIdx.y * FBM;
    const int wm = (wave >> 1) * 64, wn = (wave & 1) * 64;
    f32x4 acc[4][4] = {};
    for (int k0 = 0; k0 < K_TOTAL; k0 += FBK) {
        #pragma unroll
        for (int i = 0; i < 4; ++i) {
            const int li = i * 256 + t, row = li >> 3, c4 = li & 7;
            const float4 v = *(const float4*)(&x[(size_t)(mBase + row) * K_TOTAL + k0 + c4 * 4]);
            f16x4 hv = { (_Float16)v.x, (_Float16)v.y, (_Float16)v.z, (_Float16)v.w };
            *(f16x4*)(&As[row * LDR + c4 * 4]) = hv;
        }
        #pragma unroll
        for (int i = 0; i < 2; ++i) {
            const int li = i * 256 + t, row = li >> 2, c4 = li & 3;
            const int4 p = *(const int4*)(&wp[(size_t)(nBase + row) * KPACK + (k0 >> 1) + c4 * 4]);
            const int vals[4] = { p.x, p.y, p.z, p.w };
            f16x8 hv;
            #pragma unroll
            for (int j = 0; j < 4; ++j) {
                hv[2 * j]     = (_Float16)(( vals[j]       & 15) - 8);
                hv[2 * j + 1] = (_Float16)(((vals[j] >> 4) & 15) - 8);
            }
            *(f16x8*)(&Bs[row * LDR + c4 * 8]) = hv;
        }
        __syncthreads();
        f16x8 a[4], b[4];
        #pragma unroll
        for (int mt = 0; mt < 4; ++mt)
            a[mt] = *(const f16x8*)(&As[(wm + mt * 16 + l16) * LDR + quad * 8]);
        #pragma unroll
        for (int nt = 0; nt < 4; ++nt)
            b[nt] = *(const f16x8*)(&Bs[(wn + nt * 16 + l16) * LDR + quad * 8]);
        #pragma unroll
        for (int mt = 0; mt < 4; ++mt)
            #pragma unroll
            for (int nt = 0; nt < 4; ++nt)
                acc[mt][nt] = __builtin_amdgcn_mfma_f32_16x16x32_f16(a[mt], b[nt], acc[mt][nt], 0, 0, 0);
        __syncthreads();
    }
    #pragma unroll
    for (int nt = 0; nt < 4; ++nt) {
        const int n = nBase + wn + nt * 16 + l16;
        const float s = scale[n], bz = bias[n];
        #pragma unroll
        for (int mt = 0; mt < 4; ++mt)
            #pragma unroll
            for (int r = 0; r < 4; ++r)
                out[(size_t)(mBase + wm + mt * 16 + quad * 4 + r) * N_TOTAL + n] = acc[mt][nt][r] * s + bz;
    }
}

extern "C" void kernel_launch(void* const* d_in, const int* in_sizes, int n_in,
                              void* d_out, int out_size, void* d_ws, size_t ws_size,
                              hipStream_t stream) {
    const float* x     = (const float*)d_in[0];
    const int*   wp    = (const int*)d_in[1];
    const float* scale = (const float*)d_in[2];
    const float* bias  = (const float*)d_in[3];
    float*       out   = (float*)d_out;

    const size_t xf_bytes = (size_t)M_TOTAL * K_TOTAL * 2;              // 32 MB
    const size_t wf_bytes = (size_t)N_TOTAL * K_TOTAL * 2;              // 86 MB

    // Tri-state: 0 = untried, 1 = dynamic-LDS enabled, -1 = failed -> fallback.
    static int lds_attr_state = 0;
    if (lds_attr_state == 0) {
        hipError_t e = hipFuncSetAttribute(
            (const void*)_Int4Linear_54631984005366_kernel,
            hipFuncAttributeMaxDynamicSharedMemorySize, 65536);
        lds_attr_state = (e == hipSuccess) ? 1 : -1;
    }

    if (ws_size >= xf_bytes + wf_bytes && lds_attr_state == 1) {
        _Float16* xf = (_Float16*)d_ws;
        _Float16* wf = (_Float16*)((char*)d_ws + xf_bytes);
        // prepass: 16,777,216 floats / 8 per thread = 8192 blocks
        _Int4Linear_cvt_x<<<8192, 256, 0, stream>>>(x, xf);
        // prepass: 22,544,384 int32 / 4 per thread = 22016 blocks
        _Int4Linear_dequant_w<<<22016, 256, 0, stream>>>(wp, wf);
        // 16 m-tiles x 43 n-tiles = 688 blocks (exactly 8*86 -> clean XCD swizzle)
        _Int4Linear_54631984005366_kernel<<<dim3(688), dim3(512), 65536, stream>>>(xf, wf, scale, bias, out);
    } else {
        dim3 grid(N_TOTAL / FBN, M_TOTAL / FBM);
        _Int4Linear_fallback<<<grid, 256, 0, stream>>>(x, wp, scale, bias, out);
    }
}

// Round 9
// 754.986 us; speedup vs baseline: 1.1006x; 1.1006x over previous
//
#include <hip/hip_runtime.h>
#include <hip/hip_fp16.h>

#define M_TOTAL 4096
#define N_TOTAL 11008
#define K_TOTAL 4096
#define KPACK   2048     // int32 cols; each int32 holds ONE byte = 2 nibbles

typedef _Float16 f16x4 __attribute__((ext_vector_type(4)));
typedef _Float16 f16x8 __attribute__((ext_vector_type(8)));
typedef float    f32x4 __attribute__((ext_vector_type(4)));

// sched_group_barrier masks (LLVM SchedGroupMask, per m137)
#define SGB(mask, n) __builtin_amdgcn_sched_group_barrier((mask), (n), 0)
#define SG_MFMA  0x008
#define SG_VMEM  0x010
#define SG_DSRD  0x100

// ---------------- async 16B global -> LDS ----------------
__device__ __forceinline__ void load16_to_lds(const void* g, void* l) {
    __builtin_amdgcn_global_load_lds(
        (const __attribute__((address_space(1))) unsigned int*)g,
        (__attribute__((address_space(3))) unsigned int*)l,
        16, 0, 0);
}

// ---------------- prepass 1: x fp32 -> f16 (16.7M elems, 8/thread) ----------------
__global__ __launch_bounds__(256)
void _Int4Linear_cvt_x(const float* __restrict__ x, _Float16* __restrict__ xf) {
    const size_t i = ((size_t)blockIdx.x * 256 + threadIdx.x) * 8;
    const float4 v0 = *(const float4*)(x + i);
    const float4 v1 = *(const float4*)(x + i + 4);
    f16x8 h = { (_Float16)v0.x, (_Float16)v0.y, (_Float16)v0.z, (_Float16)v0.w,
                (_Float16)v1.x, (_Float16)v1.y, (_Float16)v1.z, (_Float16)v1.w };
    *(f16x8*)(xf + i) = h;
}

// ---------------- prepass 2: wp int32 -> f16 pairs (22.5M int32, 4/thread) ----------------
__global__ __launch_bounds__(256)
void _Int4Linear_dequant_w(const int* __restrict__ wp, _Float16* __restrict__ wf) {
    const size_t i = ((size_t)blockIdx.x * 256 + threadIdx.x) * 4;   // int32 index
    const int4 p = *(const int4*)(wp + i);
    const int v[4] = { p.x, p.y, p.z, p.w };
    f16x8 h;
    #pragma unroll
    for (int j = 0; j < 4; ++j) {
        h[2 * j]     = (_Float16)(( v[j]       & 15) - 8);
        h[2 * j + 1] = (_Float16)(((v[j] >> 4) & 15) - 8);
    }
    *(f16x8*)(wf + i * 2) = h;   // each int32 -> 2 f16
}

// ---------------- main GEMM: 256x256 tile, READ-AHEAD pipelined A-fragments ----------------
// R9 change: R2-R5 serialized because ds_reads(p) fed MFMA(p) -- a DEPENDENCY, immune
// to ordering tricks. Fix: reads issued in phase p feed phase p+1's MFMA (A-fragments
// double-buffered a0/a1); MFMA(p) runs while the LDS pipe drains reads(p+1). Raw
// s_barrier (no waitcnt) lets those reads stay outstanding across the phase boundary;
// the compiler emits a counted lgkmcnt (not 0) before MFMA(p+1). B-frags (4 reads,
// ~100cyc) stay in-phase to save 32 VGPR. SGB pins DSRD before MFMA so the scheduler
// can't hoist the (independent) MFMA burst above the reads.
// Schedule per K-tile t (2 phases, slots par=(t&1)*2, nx=((t+1)&1)*2):
//   EVEN p=2t: stage 8 (tile t+1 BOTH halves -> slots nx,nx+1); read b<-B[par](k0);
//              read-ahead a1<-A[par+1](k1); MFMA(a0,b); vmcnt(0) [own 8 stages,
//              ~1300cyc distance]; barrier
//   ODD:       read b<-B[par+1](k1); read-ahead a0<-A[nx](tile t+1 k0, staged this
//              iter's even phase + vmcnt'd + barrier'd); MFMA(a1,b); barrier
// Ledger: every slot >=1 barrier between last ds_read and restage; every read-ahead
// targets a slot drained in a PRIOR phase. Regs ~100 VGPR + 128 AGPR < 256/wave.
#define BM 256
#define BN 256
#define NKT 64          // K / 64

__global__ __launch_bounds__(512, 2)
void _Int4Linear_54631984005366_kernel(const _Float16* __restrict__ A,   // [M][K] f16
                                       const _Float16* __restrict__ B,   // [N][K] f16
                                       const float* __restrict__ scale,
                                       const float* __restrict__ bias,
                                       float*       __restrict__ out)
{
    extern __shared__ char sm[];
    char* const smA = sm;              // 4 A-slots x 16KB
    char* const smB = sm + 65536;      // 4 B-slots x 16KB

    const int t    = threadIdx.x;
    const int wave = t >> 6;
    const int lane = t & 63;
    const int l16  = lane & 15;
    const int quad = lane >> 4;
    const int wm   = wave >> 2;        // 0..1
    const int wn   = wave & 3;         // 0..3

    // XCD-aware bijective swizzle: 688 = 8 * 86 exactly; nT-major (16 consecutive share B-panel)
    const int b0 = blockIdx.x;
    const int sw = (b0 & 7) * 86 + (b0 >> 3);
    const int mBase = (sw & 15) * BM;   // 16 m-tiles
    const int nBase = (sw >> 4) * BN;   // 43 n-tiles

    // staging: round r covers rows r*128; wave covers 16 rows (1KB), lane -> (row, chunk)
    // source chunk pre-swizzled: (lane&3) ^ ((lane>>3)&3)  == chunk ^ ((row>>1)&3)
    const int srow = wave * 16 + (lane >> 2);
    const int scol = (((lane & 3) ^ ((lane >> 3) & 3)) << 3);   // halves
    const _Float16* const Ab = A + (size_t)(mBase + srow) * K_TOTAL + scol;
    const _Float16* const Bb = B + (size_t)(nBase + srow) * K_TOTAL + scol;
    const int ldst = wave * 1024;      // + r*8192 within slot (linear dest)

    // ds_read byte offsets within a slot (swizzled chunk); slot row = 64 B
    const int chA  = (quad ^ ((l16 >> 1) & 3)) << 4;
    const int aoff = (wm * 128 + l16) * 64 + chA;
    const int boff = (wn * 64  + l16) * 64 + chA;

    f32x4 acc[8][4] = {};
    f16x8 a0[8], a1[8], b[4];

    // ---- prologue: stage tile 0 (k0 -> slots A0/B0, k1 -> slots A1/B1), 8 loads ----
    load16_to_lds(Ab,                                smA + ldst);
    load16_to_lds(Ab + (size_t)128 * K_TOTAL,        smA + 8192 + ldst);
    load16_to_lds(Bb,                                smB + ldst);
    load16_to_lds(Bb + (size_t)128 * K_TOTAL,        smB + 8192 + ldst);
    load16_to_lds(Ab + 32,                           smA + 16384 + ldst);
    load16_to_lds(Ab + (size_t)128 * K_TOTAL + 32,   smA + 16384 + 8192 + ldst);
    load16_to_lds(Bb + 32,                           smB + 16384 + ldst);
    load16_to_lds(Bb + (size_t)128 * K_TOTAL + 32,   smB + 16384 + 8192 + ldst);
    asm volatile("s_waitcnt vmcnt(0)" ::: "memory");
    __builtin_amdgcn_s_barrier();
    __builtin_amdgcn_sched_barrier(0);
    // pre-read A-frags for phase 0 (slot A0)
    #pragma unroll
    for (int f = 0; f < 8; ++f) a0[f] = *(const f16x8*)(smA + aoff + f * 1024);

    for (int t0 = 0; t0 < NKT; ++t0) {
        const int par = (t0 & 1) * 2;
        const int nx  = ((t0 + 1) & 1) * 2;
        const int tn  = (t0 < NKT - 1) ? (t0 + 1) : NKT - 1;  // clamp: tail restages (never MFMA'd)
        const int kn  = tn * 64;                               // halves
        char* const AcP = smA + par * 16384;                   // (unused base, kept for clarity)
        (void)AcP;

        // ================= EVEN phase p=2*t0 =================
        {
            // stage tile tn, BOTH halves -> slots nx (k0), nx+1 (k1): 8 VMEM
            load16_to_lds(Ab + kn,                              smA + nx * 16384 + ldst);
            load16_to_lds(Ab + (size_t)128 * K_TOTAL + kn,      smA + nx * 16384 + 8192 + ldst);
            load16_to_lds(Bb + kn,                              smB + nx * 16384 + ldst);
            load16_to_lds(Bb + (size_t)128 * K_TOTAL + kn,      smB + nx * 16384 + 8192 + ldst);
            load16_to_lds(Ab + kn + 32,                         smA + (nx + 1) * 16384 + ldst);
            load16_to_lds(Ab + (size_t)128 * K_TOTAL + kn + 32, smA + (nx + 1) * 16384 + 8192 + ldst);
            load16_to_lds(Bb + kn + 32,                         smB + (nx + 1) * 16384 + ldst);
            load16_to_lds(Bb + (size_t)128 * K_TOTAL + kn + 32, smB + (nx + 1) * 16384 + 8192 + ldst);
            // cur B (k0) -- in-phase dependency, drains fast
            #pragma unroll
            for (int f = 0; f < 4; ++f) b[f] = *(const f16x8*)(smB + par * 16384 + boff + f * 1024);
            // READ-AHEAD: A-frags for odd phase (k1, slot par+1; staged >=2 phases ago)
            #pragma unroll
            for (int f = 0; f < 8; ++f) a1[f] = *(const f16x8*)(smA + (par + 1) * 16384 + aoff + f * 1024);
            // MFMA on a0 (read last phase) -- overlaps the a1 drain
            __builtin_amdgcn_s_setprio(1);
            #pragma unroll
            for (int mf = 0; mf < 8; ++mf)
                #pragma unroll
                for (int nf = 0; nf < 4; ++nf)
                    acc[mf][nf] = __builtin_amdgcn_mfma_f32_16x16x32_f16(a0[mf], b[nf], acc[mf][nf], 0, 0, 0);
            __builtin_amdgcn_s_setprio(0);
            // pin issue order: stages, then b-reads+first MFMAs, then a1-reads under MFMA
            SGB(SG_VMEM, 8);
            SGB(SG_DSRD, 4); SGB(SG_MFMA, 8);
            SGB(SG_DSRD, 8); SGB(SG_MFMA, 24);
            asm volatile("s_waitcnt vmcnt(0)" ::: "memory");   // own 8 stages landed (~1300cyc distance)
            __builtin_amdgcn_s_barrier();
            __builtin_amdgcn_sched_barrier(0);
        }

        // ================= ODD phase p=2*t0+1 =================
        {
            // cur B (k1)
            #pragma unroll
            for (int f = 0; f < 4; ++f) b[f] = *(const f16x8*)(smB + (par + 1) * 16384 + boff + f * 1024);
            // READ-AHEAD: A-frags for next even phase (tile tn k0, slot nx; staged+drained this iter)
            #pragma unroll
            for (int f = 0; f < 8; ++f) a0[f] = *(const f16x8*)(smA + nx * 16384 + aoff + f * 1024);
            // MFMA on a1 (read last phase)
            __builtin_amdgcn_s_setprio(1);
            #pragma unroll
            for (int mf = 0; mf < 8; ++mf)
                #pragma unroll
                for (int nf = 0; nf < 4; ++nf)
                    acc[mf][nf] = __builtin_amdgcn_mfma_f32_16x16x32_f16(a1[mf], b[nf], acc[mf][nf], 0, 0, 0);
            __builtin_amdgcn_s_setprio(0);
            SGB(SG_DSRD, 4); SGB(SG_MFMA, 8);
            SGB(SG_DSRD, 8); SGB(SG_MFMA, 24);
            __builtin_amdgcn_s_barrier();
            __builtin_amdgcn_sched_barrier(0);
        }
    }
    asm volatile("s_waitcnt vmcnt(0)" ::: "memory");   // safety drain before exit

    // ---- epilogue: scale/bias fused, C[m][n] with col=l16, row=quad*4+r ----
    #pragma unroll
    for (int nf = 0; nf < 4; ++nf) {
        const int n = nBase + wn * 64 + nf * 16 + l16;
        const float s  = scale[n];
        const float bz = bias[n];
        #pragma unroll
        for (int mf = 0; mf < 8; ++mf) {
            const int mb = mBase + wm * 128 + mf * 16 + quad * 4;
            #pragma unroll
            for (int r = 0; r < 4; ++r)
                out[(size_t)(mb + r) * N_TOTAL + n] = acc[mf][nf][r] * s + bz;
        }
    }
}

// ---------------- fallback: self-contained (raw inputs, static 20KB LDS, no attrs) ----------------
#define FBM 128
#define FBN 128
#define FBK 32
#define LDR 40
__global__ __launch_bounds__(256)
void _Int4Linear_fallback(const float* __restrict__ x, const int* __restrict__ wp,
                          const float* __restrict__ scale, const float* __restrict__ bias,
                          float* __restrict__ out)
{
    __shared__ _Float16 As[FBM * LDR];
    __shared__ _Float16 Bs[FBN * LDR];
    const int t = threadIdx.x, wave = t >> 6, lane = t & 63;
    const int l16 = lane & 15, quad = lane >> 4;
    const int nBase = blockIdx.x * FBN, mBase = blockIdx.y * FBM;
    const int wm = (wave >> 1) * 64, wn = (wave & 1) * 64;
    f32x4 acc[4][4] = {};
    for (int k0 = 0; k0 < K_TOTAL; k0 += FBK) {
        #pragma unroll
        for (int i = 0; i < 4; ++i) {
            const int li = i * 256 + t, row = li >> 3, c4 = li & 7;
            const float4 v = *(const float4*)(&x[(size_t)(mBase + row) * K_TOTAL + k0 + c4 * 4]);
            f16x4 hv = { (_Float16)v.x, (_Float16)v.y, (_Float16)v.z, (_Float16)v.w };
            *(f16x4*)(&As[row * LDR + c4 * 4]) = hv;
        }
        #pragma unroll
        for (int i = 0; i < 2; ++i) {
            const int li = i * 256 + t, row = li >> 2, c4 = li & 3;
            const int4 p = *(const int4*)(&wp[(size_t)(nBase + row) * KPACK + (k0 >> 1) + c4 * 4]);
            const int vals[4] = { p.x, p.y, p.z, p.w };
            f16x8 hv;
            #pragma unroll
            for (int j = 0; j < 4; ++j) {
                hv[2 * j]     = (_Float16)(( vals[j]       & 15) - 8);
                hv[2 * j + 1] = (_Float16)(((vals[j] >> 4) & 15) - 8);
            }
            *(f16x8*)(&Bs[row * LDR + c4 * 8]) = hv;
        }
        __syncthreads();
        f16x8 a[4], b[4];
        #pragma unroll
        for (int mt = 0; mt < 4; ++mt)
            a[mt] = *(const f16x8*)(&As[(wm + mt * 16 + l16) * LDR + quad * 8]);
        #pragma unroll
        for (int nt = 0; nt < 4; ++nt)
            b[nt] = *(const f16x8*)(&Bs[(wn + nt * 16 + l16) * LDR + quad * 8]);
        #pragma unroll
        for (int mt = 0; mt < 4; ++mt)
            #pragma unroll
            for (int nt = 0; nt < 4; ++nt)
                acc[mt][nt] = __builtin_amdgcn_mfma_f32_16x16x32_f16(a[mt], b[nt], acc[mt][nt], 0, 0, 0);
        __syncthreads();
    }
    #pragma unroll
    for (int nt = 0; nt < 4; ++nt) {
        const int n = nBase + wn + nt * 16 + l16;
        const float s = scale[n], bz = bias[n];
        #pragma unroll
        for (int mt = 0; mt < 4; ++mt)
            #pragma unroll
            for (int r = 0; r < 4; ++r)
                out[(size_t)(mBase + wm + mt * 16 + quad * 4 + r) * N_TOTAL + n] = acc[mt][nt][r] * s + bz;
    }
}

extern "C" void kernel_launch(void* const* d_in, const int* in_sizes, int n_in,
                              void* d_out, int out_size, void* d_ws, size_t ws_size,
                              hipStream_t stream) {
    const float* x     = (const float*)d_in[0];
    const int*   wp    = (const int*)d_in[1];
    const float* scale = (const float*)d_in[2];
    const float* bias  = (const float*)d_in[3];
    float*       out   = (float*)d_out;

    const size_t xf_bytes = (size_t)M_TOTAL * K_TOTAL * 2;              // 32 MB
    const size_t wf_bytes = (size_t)N_TOTAL * K_TOTAL * 2;              // 86 MB

    // Tri-state: 0 = untried, 1 = 128KB dynamic-LDS enabled, -1 = failed -> fallback.
    static int lds_attr_state = 0;
    if (lds_attr_state == 0) {
        hipError_t e = hipFuncSetAttribute(
            (const void*)_Int4Linear_54631984005366_kernel,
            hipFuncAttributeMaxDynamicSharedMemorySize, 131072);
        lds_attr_state = (e == hipSuccess) ? 1 : -1;
    }

    if (ws_size >= xf_bytes + wf_bytes && lds_attr_state == 1) {
        _Float16* xf = (_Float16*)d_ws;
        _Float16* wf = (_Float16*)((char*)d_ws + xf_bytes);
        // prepass: 16,777,216 floats / 8 per thread = 8192 blocks
        _Int4Linear_cvt_x<<<8192, 256, 0, stream>>>(x, xf);
        // prepass: 22,544,384 int32 / 4 per thread = 22016 blocks
        _Int4Linear_dequant_w<<<22016, 256, 0, stream>>>(wp, wf);
        // 16 m-tiles x 43 n-tiles = 688 blocks (exactly 8*86 -> clean XCD swizzle)
        _Int4Linear_54631984005366_kernel<<<dim3(688), dim3(512), 131072, stream>>>(xf, wf, scale, bias, out);
    } else {
        dim3 grid(N_TOTAL / FBN, M_TOTAL / FBM);
        _Int4Linear_fallback<<<grid, 256, 0, stream>>>(x, wp, scale, bias, out);
    }
}

// Round 10
// 644.310 us; speedup vs baseline: 1.2897x; 1.1718x over previous
//
#include <hip/hip_runtime.h>
#include <hip/hip_fp16.h>

#define M_TOTAL 4096
#define N_TOTAL 11008
#define K_TOTAL 4096
#define KPACK   2048     // int32 cols; each int32 holds ONE byte = 2 nibbles

typedef _Float16 f16x4  __attribute__((ext_vector_type(4)));
typedef _Float16 f16x8  __attribute__((ext_vector_type(8)));
typedef float    f32x4  __attribute__((ext_vector_type(4)));
typedef float    f32x16 __attribute__((ext_vector_type(16)));

// ---------------- async 16B global -> LDS ----------------
__device__ __forceinline__ void load16_to_lds(const void* g, void* l) {
    __builtin_amdgcn_global_load_lds(
        (const __attribute__((address_space(1))) unsigned int*)g,
        (__attribute__((address_space(3))) unsigned int*)l,
        16, 0, 0);
}

// ---------------- merged prepass: blocks [0,8192) cvt x; [8192,30208) dequant w ----------------
__global__ __launch_bounds__(256)
void _Int4Linear_prep(const float* __restrict__ x, _Float16* __restrict__ xf,
                      const int* __restrict__ wp, _Float16* __restrict__ wf) {
    const int bid = blockIdx.x;
    if (bid < 8192) {
        const size_t i = ((size_t)bid * 256 + threadIdx.x) * 8;
        const float4 v0 = *(const float4*)(x + i);
        const float4 v1 = *(const float4*)(x + i + 4);
        f16x8 h = { (_Float16)v0.x, (_Float16)v0.y, (_Float16)v0.z, (_Float16)v0.w,
                    (_Float16)v1.x, (_Float16)v1.y, (_Float16)v1.z, (_Float16)v1.w };
        *(f16x8*)(xf + i) = h;
    } else {
        const size_t i = ((size_t)(bid - 8192) * 256 + threadIdx.x) * 4;   // int32 index
        const int4 p = *(const int4*)(wp + i);
        const int v[4] = { p.x, p.y, p.z, p.w };
        f16x8 h;
        #pragma unroll
        for (int j = 0; j < 4; ++j) {
            h[2 * j]     = (_Float16)(( v[j]       & 15) - 8);
            h[2 * j + 1] = (_Float16)(((v[j] >> 4) & 15) - 8);
        }
        *(f16x8*)(wf + i * 2) = h;   // each int32 -> 2 f16
    }
}

// ---------------- main GEMM: R4 skeleton, 32x32x16 MFMA (higher pipe rate) ----------------
// R10 change: R4's 2550 cyc/phase = serial {ds_read ~1150} + {MFMA ~1240} + {writes
// ~300}; 4 re-ordering attempts (R3/R5/R9) and tile changes (R6/R8) all regressed ->
// shrink a TERM instead. mfma_f32_32x32x16_f16 runs at 2382 TF vs 16x16's 2075 (+15%
// pipe rate): MFMA term 1240 -> ~1024 cyc, instruction count halves (16/wave/phase).
// LDS pattern unchanged: 12 ds_read_b128/wave/phase, bank-uniform under the same
// chunk-XOR layout (verified: 8 accesses/bank = b128 minimum, zero extra conflicts).
// Staging, counted-vmcnt(4) ledger, barriers, XCD swizzle: byte-identical to R4.
// Fragments (m74/m101 HW-verified): A/B lane&31 = row, lane>>5 = k-half (8 halves);
// C/D: col = lane&31 (n side), row = (reg&3) + 8*(reg>>2) + 4*(lane>>5) (m side).
#define BM 256
#define BN 256
#define NKT 64          // K / 64

__global__ __launch_bounds__(512, 2)
void _Int4Linear_54631984005366_kernel(const _Float16* __restrict__ A,   // [M][K] f16
                                       const _Float16* __restrict__ B,   // [N][K] f16
                                       const float* __restrict__ scale,
                                       const float* __restrict__ bias,
                                       float*       __restrict__ out)
{
    extern __shared__ char sm[];
    char* const smA = sm;              // 4 A-slots x 16KB (slot = 256 rows x 64 B)
    char* const smB = sm + 65536;      // 4 B-slots x 16KB

    const int t    = threadIdx.x;
    const int wave = t >> 6;
    const int lane = t & 63;
    const int l31  = lane & 31;
    const int h    = lane >> 5;        // 0..1 : k-half selector for 32x32 frags
    const int wm   = wave >> 2;        // 0..1
    const int wn   = wave & 3;         // 0..3

    // XCD-aware bijective swizzle: 688 = 8 * 86 exactly; nT-major (16 consecutive share B-panel)
    const int b0 = blockIdx.x;
    const int sw = (b0 & 7) * 86 + (b0 >> 3);
    const int mBase = (sw & 15) * BM;   // 16 m-tiles
    const int nBase = (sw >> 4) * BN;   // 43 n-tiles

    // staging (unchanged from R4): wave covers 16 rows (1KB), lane -> (row, chunk)
    // source chunk pre-swizzled: (lane&3) ^ ((lane>>3)&3)  == chunk ^ ((row>>1)&3)
    const int srow = wave * 16 + (lane >> 2);
    const int scol = (((lane & 3) ^ ((lane >> 3) & 3)) << 3);   // halves
    const _Float16* const Ab = A + (size_t)(mBase + srow) * K_TOTAL + scol;
    const _Float16* const Bb = B + (size_t)(nBase + srow) * K_TOTAL + scol;
    const int ldst = wave * 1024;      // + r*8192 within slot (linear dest)

    // ds_read offsets (32x32 frags): row = base + l31, logical chunk (ks*2+h),
    // physical chunk = (ks*2+h) ^ ((row>>1)&3); base rows are multiples of 32 -> s = (l31>>1)&3
    const int sA    = (l31 >> 1) & 3;
    const int aBase = (wm * 128 + l31) * 64;   // + mb*2048 + pc*16
    const int bBase = (wn * 64  + l31) * 64;   // + nb*2048 + pc*16
    const int pc0   = ((0 * 2 + h) ^ sA) << 4; // ks=0
    const int pc1   = ((1 * 2 + h) ^ sA) << 4; // ks=1

    f32x16 acc[4][2] = {};   // [mb][nb], 128 AGPRs

    // ---- prologue: stage K-tile 0, order A-k0, B-k0, A-k1, B-k1 (8 loads) ----
    #pragma unroll
    for (int r = 0; r < 2; ++r) load16_to_lds(Ab + (size_t)r * 128 * K_TOTAL,      smA + r * 8192 + ldst);
    #pragma unroll
    for (int r = 0; r < 2; ++r) load16_to_lds(Bb + (size_t)r * 128 * K_TOTAL,      smB + r * 8192 + ldst);
    #pragma unroll
    for (int r = 0; r < 2; ++r) load16_to_lds(Ab + (size_t)r * 128 * K_TOTAL + 32, smA + 16384 + r * 8192 + ldst);
    #pragma unroll
    for (int r = 0; r < 2; ++r) load16_to_lds(Bb + (size_t)r * 128 * K_TOTAL + 32, smB + 16384 + r * 8192 + ldst);
    asm volatile("s_waitcnt vmcnt(4)" ::: "memory");   // k0 pair landed (own wave); barrier = all waves
    __builtin_amdgcn_s_barrier();
    __builtin_amdgcn_sched_barrier(0);

    #pragma unroll 2
    for (int t0 = 0; t0 < NKT; ++t0) {
        const int par = (t0 & 1) * 2;
        const int nxp = ((t0 + 1) & 1) * 2;
        const int tn  = (t0 < NKT - 1) ? (t0 + 1) : t0;   // clamp: last segment re-stages (never read)
        const int kn  = tn * 64;                          // halves
        char* const Ac0 = smA + (par    ) * 16384;
        char* const Ac1 = smA + (par + 1) * 16384;
        char* const Bc0 = smB + (par    ) * 16384;
        char* const Bc1 = smB + (par + 1) * 16384;
        char* const An0 = smA + (nxp    ) * 16384;
        char* const An1 = smA + (nxp + 1) * 16384;
        char* const Bn0 = smB + (nxp    ) * 16384;
        char* const Bn1 = smB + (nxp + 1) * 16384;

        // ========== phase A: kh0 -- stages next k0 pair; reads Ac0/Bc0; 16 MFMA ==========
        {
            #pragma unroll
            for (int r = 0; r < 2; ++r) load16_to_lds(Ab + (size_t)r * 128 * K_TOTAL + kn, An0 + r * 8192 + ldst);
            #pragma unroll
            for (int r = 0; r < 2; ++r) load16_to_lds(Bb + (size_t)r * 128 * K_TOTAL + kn, Bn0 + r * 8192 + ldst);
            f16x8 a[4][2], b[2][2];
            b[0][0] = *(const f16x8*)(Bc0 + bBase + pc0);
            #pragma unroll
            for (int mb = 0; mb < 4; ++mb) a[mb][0] = *(const f16x8*)(Ac0 + aBase + mb * 2048 + pc0);
            b[1][0] = *(const f16x8*)(Bc0 + bBase + 2048 + pc0);
            b[0][1] = *(const f16x8*)(Bc0 + bBase + pc1);
            b[1][1] = *(const f16x8*)(Bc0 + bBase + 2048 + pc1);
            #pragma unroll
            for (int mb = 0; mb < 4; ++mb) a[mb][1] = *(const f16x8*)(Ac0 + aBase + mb * 2048 + pc1);
            __builtin_amdgcn_s_setprio(1);
            #pragma unroll
            for (int ks = 0; ks < 2; ++ks)
                #pragma unroll
                for (int mb = 0; mb < 4; ++mb)
                    #pragma unroll
                    for (int nb = 0; nb < 2; ++nb)
                        acc[mb][nb] = __builtin_amdgcn_mfma_f32_32x32x16_f16(a[mb][ks], b[nb][ks], acc[mb][nb], 0, 0, 0);
            __builtin_amdgcn_s_setprio(0);
            // curr k1 pair (issued prev phase B; prologue for t0=0) landed: newer = this phase's 4
            asm volatile("s_waitcnt vmcnt(4)" ::: "memory");
            __builtin_amdgcn_s_barrier();
            __builtin_amdgcn_sched_barrier(0);
        }

        // ========== phase B: kh1 -- stages next k1 pair; reads Ac1/Bc1; 16 MFMA ==========
        {
            #pragma unroll
            for (int r = 0; r < 2; ++r) load16_to_lds(Ab + (size_t)r * 128 * K_TOTAL + kn + 32, An1 + r * 8192 + ldst);
            #pragma unroll
            for (int r = 0; r < 2; ++r) load16_to_lds(Bb + (size_t)r * 128 * K_TOTAL + kn + 32, Bn1 + r * 8192 + ldst);
            f16x8 a[4][2], b[2][2];
            b[0][0] = *(const f16x8*)(Bc1 + bBase + pc0);
            #pragma unroll
            for (int mb = 0; mb < 4; ++mb) a[mb][0] = *(const f16x8*)(Ac1 + aBase + mb * 2048 + pc0);
            b[1][0] = *(const f16x8*)(Bc1 + bBase + 2048 + pc0);
            b[0][1] = *(const f16x8*)(Bc1 + bBase + pc1);
            b[1][1] = *(const f16x8*)(Bc1 + bBase + 2048 + pc1);
            #pragma unroll
            for (int mb = 0; mb < 4; ++mb) a[mb][1] = *(const f16x8*)(Ac1 + aBase + mb * 2048 + pc1);
            __builtin_amdgcn_s_setprio(1);
            #pragma unroll
            for (int ks = 0; ks < 2; ++ks)
                #pragma unroll
                for (int mb = 0; mb < 4; ++mb)
                    #pragma unroll
                    for (int nb = 0; nb < 2; ++nb)
                        acc[mb][nb] = __builtin_amdgcn_mfma_f32_32x32x16_f16(a[mb][ks], b[nb][ks], acc[mb][nb], 0, 0, 0);
            __builtin_amdgcn_s_setprio(0);
            // next k0 pair (issued this phase A) landed: newer = this phase's 4
            asm volatile("s_waitcnt vmcnt(4)" ::: "memory");
            __builtin_amdgcn_s_barrier();
            __builtin_amdgcn_sched_barrier(0);
        }
    }
    asm volatile("s_waitcnt vmcnt(0)" ::: "memory");   // drain clamped tail stages before exit

    // ---- epilogue: scale/bias fused; 32x32 C/D: col = l31 (n), row = (i&3)+8*(i>>2)+4*h (m) ----
    #pragma unroll
    for (int nb = 0; nb < 2; ++nb) {
        const int n = nBase + wn * 64 + nb * 32 + l31;
        const float s  = scale[n];
        const float bz = bias[n];
        #pragma unroll
        for (int mb = 0; mb < 4; ++mb) {
            const int mb0 = mBase + wm * 128 + mb * 32 + 4 * h;
            #pragma unroll
            for (int i = 0; i < 16; ++i) {
                const int m = mb0 + (i & 3) + 8 * (i >> 2);
                out[(size_t)m * N_TOTAL + n] = acc[mb][nb][i] * s + bz;
            }
        }
    }
}

// ---------------- fallback: self-contained (raw inputs, static 20KB LDS, no attrs) ----------------
#define FBM 128
#define FBN 128
#define FBK 32
#define LDR 40
__global__ __launch_bounds__(256)
void _Int4Linear_fallback(const float* __restrict__ x, const int* __restrict__ wp,
                          const float* __restrict__ scale, const float* __restrict__ bias,
                          float* __restrict__ out)
{
    __shared__ _Float16 As[FBM * LDR];
    __shared__ _Float16 Bs[FBN * LDR];
    const int t = threadIdx.x, wave = t >> 6, lane = t & 63;
    const int l16 = lane & 15, quad = lane >> 4;
    const int nBase = blockIdx.x * FBN, mBase = blockIdx.y * FBM;
    const int wm = (wave >> 1) * 64, wn = (wave & 1) * 64;
    f32x4 acc[4][4] = {};
    for (int k0 = 0; k0 < K_TOTAL; k0 += FBK) {
        #pragma unroll
        for (int i = 0; i < 4; ++i) {
            const int li = i * 256 + t, row = li >> 3, c4 = li & 7;
            const float4 v = *(const float4*)(&x[(size_t)(mBase + row) * K_TOTAL + k0 + c4 * 4]);
            f16x4 hv = { (_Float16)v.x, (_Float16)v.y, (_Float16)v.z, (_Float16)v.w };
            *(f16x4*)(&As[row * LDR + c4 * 4]) = hv;
        }
        #pragma unroll
        for (int i = 0; i < 2; ++i) {
            const int li = i * 256 + t, row = li >> 2, c4 = li & 3;
            const int4 p = *(const int4*)(&wp[(size_t)(nBase + row) * KPACK + (k0 >> 1) + c4 * 4]);
            const int vals[4] = { p.x, p.y, p.z, p.w };
            f16x8 hv;
            #pragma unroll
            for (int j = 0; j < 4; ++j) {
                hv[2 * j]     = (_Float16)(( vals[j]       & 15) - 8);
                hv[2 * j + 1] = (_Float16)(((vals[j] >> 4) & 15) - 8);
            }
            *(f16x8*)(&Bs[row * LDR + c4 * 8]) = hv;
        }
        __syncthreads();
        f16x8 a[4], b[4];
        #pragma unroll
        for (int mt = 0; mt < 4; ++mt)
            a[mt] = *(const f16x8*)(&As[(wm + mt * 16 + l16) * LDR + quad * 8]);
        #pragma unroll
        for (int nt = 0; nt < 4; ++nt)
            b[nt] = *(const f16x8*)(&Bs[(wn + nt * 16 + l16) * LDR + quad * 8]);
        #pragma unroll
        for (int mt = 0; mt < 4; ++mt)
            #pragma unroll
            for (int nt = 0; nt < 4; ++nt)
                acc[mt][nt] = __builtin_amdgcn_mfma_f32_16x16x32_f16(a[mt], b[nt], acc[mt][nt], 0, 0, 0);
        __syncthreads();
    }
    #pragma unroll
    for (int nt = 0; nt < 4; ++nt) {
        const int n = nBase + wn + nt * 16 + l16;
        const float s = scale[n], bz = bias[n];
        #pragma unroll
        for (int mt = 0; mt < 4; ++mt)
            #pragma unroll
            for (int r = 0; r < 4; ++r)
                out[(size_t)(mBase + wm + mt * 16 + quad * 4 + r) * N_TOTAL + n] = acc[mt][nt][r] * s + bz;
    }
}

extern "C" void kernel_launch(void* const* d_in, const int* in_sizes, int n_in,
                              void* d_out, int out_size, void* d_ws, size_t ws_size,
                              hipStream_t stream) {
    const float* x     = (const float*)d_in[0];
    const int*   wp    = (const int*)d_in[1];
    const float* scale = (const float*)d_in[2];
    const float* bias  = (const float*)d_in[3];
    float*       out   = (float*)d_out;

    const size_t xf_bytes = (size_t)M_TOTAL * K_TOTAL * 2;              // 32 MB
    const size_t wf_bytes = (size_t)N_TOTAL * K_TOTAL * 2;              // 86 MB

    // Tri-state: 0 = untried, 1 = 128KB dynamic-LDS enabled, -1 = failed -> fallback.
    static int lds_attr_state = 0;
    if (lds_attr_state == 0) {
        hipError_t e = hipFuncSetAttribute(
            (const void*)_Int4Linear_54631984005366_kernel,
            hipFuncAttributeMaxDynamicSharedMemorySize, 131072);
        lds_attr_state = (e == hipSuccess) ? 1 : -1;
    }

    if (ws_size >= xf_bytes + wf_bytes && lds_attr_state == 1) {
        _Float16* xf = (_Float16*)d_ws;
        _Float16* wf = (_Float16*)((char*)d_ws + xf_bytes);
        // merged prepass: 8192 cvt-blocks + 22016 dequant-blocks = 30208 (one launch)
        _Int4Linear_prep<<<30208, 256, 0, stream>>>(x, xf, wp, wf);
        // 16 m-tiles x 43 n-tiles = 688 blocks (exactly 8*86 -> clean XCD swizzle)
        _Int4Linear_54631984005366_kernel<<<dim3(688), dim3(512), 131072, stream>>>(xf, wf, scale, bias, out);
    } else {
        dim3 grid(N_TOTAL / FBN, M_TOTAL / FBM);
        _Int4Linear_fallback<<<grid, 256, 0, stream>>>(x, wp, scale, bias, out);
    }
}